// Round 14
// baseline (804.694 us; speedup 1.0000x reference)
//
#include <hip/hip_runtime.h>

#define N_NODES 100000
#define N_EDGES 1600000
#define T_STEPS 6
#define FDIM    64
#define SEG     (T_STEPS * N_NODES)
#define C2      0.01f
#define PADF    68   // LDS row stride: 17 quads; (u+q)%8 -> minimum-aliasing b128

// Build per-(t,dst)-segment linked lists over edges. One atomicExch per edge
// on the 2.4MB head array (L2-resident).
__global__ __launch_bounds__(256) void k_build(
    const int* __restrict__ dst, const int* __restrict__ tix,
    int* __restrict__ head, int* __restrict__ nxt)
{
  const int e = blockIdx.x * blockDim.x + threadIdx.x;
  if (e >= N_EDGES) return;
  const int key = tix[e] * N_NODES + dst[e];
  nxt[e] = atomicExch(&head[key], e);
}

// ===== VERBATIM r13 k_sum6 (branchless 6-chain interleave) -- keep. =====
__global__ __launch_bounds__(256) void k_sum6(
    const float* __restrict__ feat, const int* __restrict__ src,
    const int* __restrict__ head, const int* __restrict__ nxt,
    float* __restrict__ sums, float* __restrict__ cnt)
{
  const int lane = threadIdx.x & 63;
  const int n = blockIdx.x * (blockDim.x >> 6) + (threadIdx.x >> 6);
  if (n >= N_NODES) return;

  int e0 = head[(size_t)0 * N_NODES + n];
  int e1 = head[(size_t)1 * N_NODES + n];
  int e2 = head[(size_t)2 * N_NODES + n];
  int e3 = head[(size_t)3 * N_NODES + n];
  int e4 = head[(size_t)4 * N_NODES + n];
  int e5 = head[(size_t)5 * N_NODES + n];

  float v0 = 0.f, v1 = 0.f, v2 = 0.f, v3 = 0.f, v4 = 0.f, v5 = 0.f;
  int c0 = 0, c1 = 0, c2 = 0, c3 = 0, c4 = 0, c5 = 0;

  while ((e0 >= 0) | (e1 >= 0) | (e2 >= 0) | (e3 >= 0) | (e4 >= 0) | (e5 >= 0)) {
    const int a0 = e0 < 0 ? 0 : e0, a1 = e1 < 0 ? 0 : e1, a2 = e2 < 0 ? 0 : e2;
    const int a3 = e3 < 0 ? 0 : e3, a4 = e4 < 0 ? 0 : e4, a5 = e5 < 0 ? 0 : e5;

    const int s0 = src[a0], s1 = src[a1], s2 = src[a2];
    const int s3 = src[a3], s4 = src[a4], s5 = src[a5];
    const int x0 = nxt[a0], x1 = nxt[a1], x2 = nxt[a2];
    const int x3 = nxt[a3], x4 = nxt[a4], x5 = nxt[a5];

    const float f0 = feat[(size_t)s0 * FDIM + lane];
    const float f1 = feat[(size_t)s1 * FDIM + lane];
    const float f2 = feat[(size_t)s2 * FDIM + lane];
    const float f3 = feat[(size_t)s3 * FDIM + lane];
    const float f4 = feat[(size_t)s4 * FDIM + lane];
    const float f5 = feat[(size_t)s5 * FDIM + lane];

    v0 += (e0 >= 0) ? f0 : 0.0f;  c0 += (e0 >= 0);  e0 = (e0 >= 0) ? x0 : -1;
    v1 += (e1 >= 0) ? f1 : 0.0f;  c1 += (e1 >= 0);  e1 = (e1 >= 0) ? x1 : -1;
    v2 += (e2 >= 0) ? f2 : 0.0f;  c2 += (e2 >= 0);  e2 = (e2 >= 0) ? x2 : -1;
    v3 += (e3 >= 0) ? f3 : 0.0f;  c3 += (e3 >= 0);  e3 = (e3 >= 0) ? x3 : -1;
    v4 += (e4 >= 0) ? f4 : 0.0f;  c4 += (e4 >= 0);  e4 = (e4 >= 0) ? x4 : -1;
    v5 += (e5 >= 0) ? f5 : 0.0f;  c5 += (e5 >= 0);  e5 = (e5 >= 0) ? x5 : -1;
  }

  sums[((size_t)0 * N_NODES + n) * FDIM + lane] = v0;
  sums[((size_t)1 * N_NODES + n) * FDIM + lane] = v1;
  sums[((size_t)2 * N_NODES + n) * FDIM + lane] = v2;
  sums[((size_t)3 * N_NODES + n) * FDIM + lane] = v3;
  sums[((size_t)4 * N_NODES + n) * FDIM + lane] = v4;
  sums[((size_t)5 * N_NODES + n) * FDIM + lane] = v5;
  if (lane == 0) {
    cnt[(size_t)0 * N_NODES + n] = (float)c0;
    cnt[(size_t)1 * N_NODES + n] = (float)c1;
    cnt[(size_t)2 * N_NODES + n] = (float)c2;
    cnt[(size_t)3 * N_NODES + n] = (float)c3;
    cnt[(size_t)4 * N_NODES + n] = (float)c4;
    cnt[(size_t)5 * N_NODES + n] = (float)c5;
  }
}

// LDS-staged gemm, per-t tile, DOUBLE-BUFFERED (r13 post-mortem: stage ->
// barrier -> compute serialized 6 L3 latencies on the critical path;
// VALUBusy 33%, 2/3 stall). Per iteration: issue t+1's 4 global float4 loads
// into registers, compute t from lds[t&1] (latency hides under ~2300cy of
// fma), write regs to lds[(t+1)&1], ONE barrier. Pass A/B arithmetic and the
// staging copy are verbatim r13 -> bit-identical output.
template <int OUTF, int JBLK>
__global__ __launch_bounds__(256) void k_gemm_db(
    const float* __restrict__ sums, const float* __restrict__ cnt,
    const float* __restrict__ W, const float* __restrict__ bias,
    float* __restrict__ out)
{
  __shared__ float lds[2][64 * PADF];   // 2 x 17408 B
  const int tid = threadIdx.x;
  const int lane = tid & 63;
  const int n0 = blockIdx.x * 64;
  const int jb = __builtin_amdgcn_readfirstlane(tid >> 6) * JBLK;

  int n = n0 + lane;
  const bool valid = (n < N_NODES);
  if (!valid) n = N_NODES - 1;

  // staging item mapping: 4 items/thread (item = tid + it*256)
  int sq[4], su[4];
  bool sok[4];
  #pragma unroll
  for (int it = 0; it < 4; ++it) {
    const int item = tid + it * 256;
    sq[it] = item & 15;
    su[it] = item >> 4;
    sok[it] = (n0 + su[it]) < N_NODES;
  }

  // prefetch all 6 cnt values (same loads as r13 pass A, hoisted)
  float cv[T_STEPS];
  #pragma unroll
  for (int t = 0; t < T_STEPS; ++t) cv[t] = cnt[(size_t)t * N_NODES + n];

  float4 reg[4];
  #pragma unroll
  for (int it = 0; it < 4; ++it) {
    reg[it] = make_float4(0.f, 0.f, 0.f, 0.f);
    if (sok[it])
      reg[it] = *(const float4*)(sums + ((size_t)0 * N_NODES + n0 + su[it]) * FDIM + sq[it] * 4);
  }
  #pragma unroll
  for (int it = 0; it < 4; ++it)
    *(float4*)(&lds[0][su[it] * PADF + sq[it] * 4]) = reg[it];
  __syncthreads();

  float acc[JBLK];
  #pragma unroll
  for (int j = 0; j < JBLK; ++j) acc[j] = bias[jb + j];

  #pragma unroll 1
  for (int t = 0; t < T_STEPS; ++t) {
    // issue next tile's global loads (consumed only at the ds_write below)
    if (t + 1 < T_STEPS) {
      #pragma unroll
      for (int it = 0; it < 4; ++it) {
        reg[it] = make_float4(0.f, 0.f, 0.f, 0.f);
        if (sok[it])
          reg[it] = *(const float4*)(sums + ((size_t)(t + 1) * N_NODES + n0 + su[it]) * FDIM + sq[it] * 4);
      }
    }

    const float* buf = lds[t & 1];

    // ---- pass A for this t (verbatim r1 rounding) ----
    const float rc = 1.0f / fmaxf(cv[t], 1.0f);
    const float4* row = (const float4*)(buf + lane * PADF);
    float ss = 0.0f;
    #pragma unroll
    for (int q = 0; q < FDIM / 4; ++q) {
      float4 v = row[q];
      float m0 = v.x * rc, m1 = v.y * rc, m2 = v.z * rc, m3 = v.w * rc;
      ss += m0 * m0 + m1 * m1 + m2 * m2 + m3 * m3;
    }
    const float norm = 1.0f - C2 * ss;
    const float s = rc / norm;

    // ---- pass B partial for this t, j-slice [jb, jb+JBLK) ----
    #pragma unroll
    for (int q8 = 0; q8 < FDIM / 8; ++q8) {
      const float4 a = row[q8 * 2 + 0];
      const float4 b4 = row[q8 * 2 + 1];
      const float hv[8] = {a.x, a.y, a.z, a.w, b4.x, b4.y, b4.z, b4.w};
      const float* wr = W + ((size_t)t * FDIM + q8 * 8) * OUTF + jb;
      #pragma unroll
      for (int i = 0; i < 8; ++i) {
        const float hs = hv[i] * s;
        #pragma unroll
        for (int j = 0; j < JBLK; ++j)
          acc[j] = fmaf(hs, wr[i * OUTF + j], acc[j]);
      }
    }

    // write next tile (waitcnt lands here, after compute) + one barrier
    if (t + 1 < T_STEPS) {
      #pragma unroll
      for (int it = 0; it < 4; ++it)
        *(float4*)(&lds[(t + 1) & 1][su[it] * PADF + sq[it] * 4]) = reg[it];
    }
    __syncthreads();
  }

  if (valid) {
    float* o = out + (size_t)n * OUTF + jb;
    #pragma unroll
    for (int j = 0; j < JBLK; ++j) o[j] = fmaxf(acc[j], 0.0f);
  }
}

extern "C" void kernel_launch(void* const* d_in, const int* in_sizes, int n_in,
                              void* d_out, int out_size, void* d_ws, size_t ws_size,
                              hipStream_t stream) {
  const float* x  = (const float*)d_in[0];
  const int*  ei  = (const int*)d_in[1];
  const int*  tix = (const int*)d_in[2];
  const float* W1 = (const float*)d_in[3];
  const float* b1 = (const float*)d_in[4];
  const float* W2 = (const float*)d_in[5];
  const float* b2 = (const float*)d_in[6];

  const int* src = ei;
  const int* dst = ei + N_EDGES;

  // Workspace: head[SEG] | nxt[NE] | sums[SEG*64] | cnt[SEG] | h1[NN*64]
  int*   head = (int*)d_ws;
  int*   nxt  = head + SEG;
  float* sums = (float*)(nxt + N_EDGES);
  float* cnt  = sums + (size_t)SEG * FDIM;
  float* h1   = cnt + SEG;

  const int sum_grid = (N_NODES + 3) / 4;        // k_sum6: 4 waves/block
  const int ngrp     = (N_NODES + 63) / 64;      // 1563 64-node groups

  hipMemsetAsync(head, 0xFF, (size_t)SEG * sizeof(int), stream);
  k_build<<<(N_EDGES + 255) / 256, 256, 0, stream>>>(dst, tix, head, nxt);

  // Layer 1
  k_sum6<<<sum_grid, 256, 0, stream>>>(x, src, head, nxt, sums, cnt);
  k_gemm_db<64, 16><<<ngrp, 256, 0, stream>>>(sums, cnt, W1, b1, h1);

  // Layer 2 (same edge lists; cnt identical but rewritten -- harmless)
  k_sum6<<<sum_grid, 256, 0, stream>>>(h1, src, head, nxt, sums, cnt);
  k_gemm_db<16, 4><<<ngrp, 256, 0, stream>>>(sums, cnt, W2, b2, (float*)d_out);
}

// Round 15
// 632.030 us; speedup vs baseline: 1.2732x; 1.2732x over previous
//
#include <hip/hip_runtime.h>

#define N_NODES 100000
#define N_EDGES 1600000
#define T_STEPS 6
#define FDIM    64
#define SEG     (T_STEPS * N_NODES)
#define C2      0.01f
#define PADF    68   // LDS row stride: 17 quads, 16B-aligned float4 rows

// Build per-(t,dst)-segment linked lists over edges. One atomicExch per edge
// on the 2.4MB head array (L2-resident).
__global__ __launch_bounds__(256) void k_build(
    const int* __restrict__ dst, const int* __restrict__ tix,
    int* __restrict__ head, int* __restrict__ nxt)
{
  const int e = blockIdx.x * blockDim.x + threadIdx.x;
  if (e >= N_EDGES) return;
  const int key = tix[e] * N_NODES + dst[e];
  nxt[e] = atomicExch(&head[key], e);
}

// ===== VERBATIM r13 k_sum6 (branchless 6-chain interleave, 118us) =====
__global__ __launch_bounds__(256) void k_sum6(
    const float* __restrict__ feat, const int* __restrict__ src,
    const int* __restrict__ head, const int* __restrict__ nxt,
    float* __restrict__ sums, float* __restrict__ cnt)
{
  const int lane = threadIdx.x & 63;
  const int n = blockIdx.x * (blockDim.x >> 6) + (threadIdx.x >> 6);
  if (n >= N_NODES) return;

  int e0 = head[(size_t)0 * N_NODES + n];
  int e1 = head[(size_t)1 * N_NODES + n];
  int e2 = head[(size_t)2 * N_NODES + n];
  int e3 = head[(size_t)3 * N_NODES + n];
  int e4 = head[(size_t)4 * N_NODES + n];
  int e5 = head[(size_t)5 * N_NODES + n];

  float v0 = 0.f, v1 = 0.f, v2 = 0.f, v3 = 0.f, v4 = 0.f, v5 = 0.f;
  int c0 = 0, c1 = 0, c2 = 0, c3 = 0, c4 = 0, c5 = 0;

  while ((e0 >= 0) | (e1 >= 0) | (e2 >= 0) | (e3 >= 0) | (e4 >= 0) | (e5 >= 0)) {
    const int a0 = e0 < 0 ? 0 : e0, a1 = e1 < 0 ? 0 : e1, a2 = e2 < 0 ? 0 : e2;
    const int a3 = e3 < 0 ? 0 : e3, a4 = e4 < 0 ? 0 : e4, a5 = e5 < 0 ? 0 : e5;

    const int s0 = src[a0], s1 = src[a1], s2 = src[a2];
    const int s3 = src[a3], s4 = src[a4], s5 = src[a5];
    const int x0 = nxt[a0], x1 = nxt[a1], x2 = nxt[a2];
    const int x3 = nxt[a3], x4 = nxt[a4], x5 = nxt[a5];

    const float f0 = feat[(size_t)s0 * FDIM + lane];
    const float f1 = feat[(size_t)s1 * FDIM + lane];
    const float f2 = feat[(size_t)s2 * FDIM + lane];
    const float f3 = feat[(size_t)s3 * FDIM + lane];
    const float f4 = feat[(size_t)s4 * FDIM + lane];
    const float f5 = feat[(size_t)s5 * FDIM + lane];

    v0 += (e0 >= 0) ? f0 : 0.0f;  c0 += (e0 >= 0);  e0 = (e0 >= 0) ? x0 : -1;
    v1 += (e1 >= 0) ? f1 : 0.0f;  c1 += (e1 >= 0);  e1 = (e1 >= 0) ? x1 : -1;
    v2 += (e2 >= 0) ? f2 : 0.0f;  c2 += (e2 >= 0);  e2 = (e2 >= 0) ? x2 : -1;
    v3 += (e3 >= 0) ? f3 : 0.0f;  c3 += (e3 >= 0);  e3 = (e3 >= 0) ? x3 : -1;
    v4 += (e4 >= 0) ? f4 : 0.0f;  c4 += (e4 >= 0);  e4 = (e4 >= 0) ? x4 : -1;
    v5 += (e5 >= 0) ? f5 : 0.0f;  c5 += (e5 >= 0);  e5 = (e5 >= 0) ? x5 : -1;
  }

  sums[((size_t)0 * N_NODES + n) * FDIM + lane] = v0;
  sums[((size_t)1 * N_NODES + n) * FDIM + lane] = v1;
  sums[((size_t)2 * N_NODES + n) * FDIM + lane] = v2;
  sums[((size_t)3 * N_NODES + n) * FDIM + lane] = v3;
  sums[((size_t)4 * N_NODES + n) * FDIM + lane] = v4;
  sums[((size_t)5 * N_NODES + n) * FDIM + lane] = v5;
  if (lane == 0) {
    cnt[(size_t)0 * N_NODES + n] = (float)c0;
    cnt[(size_t)1 * N_NODES + n] = (float)c1;
    cnt[(size_t)2 * N_NODES + n] = (float)c2;
    cnt[(size_t)3 * N_NODES + n] = (float)c3;
    cnt[(size_t)4 * N_NODES + n] = (float)c4;
    cnt[(size_t)5 * N_NODES + n] = (float)c5;
  }
}

// r13 gemm body VERBATIM (147us, proven), with ONE change: 8 waves/block
// (512 threads) x JBLK = OUTF/8 j-slices instead of 4 x OUTF/4.
//  - r14 lesson: no explicit double-buffer (runtime-indexed LDS + prefetch
//    regs -> VGPR 76, occ 28%, 405us). Compiler's schedule wins.
//  - r13 evidence: gemm<16> == gemm<64> time -> shared stage/latency-bound
//    at 6252 waves total (6.1/CU). Doubling waves per block doubles what
//    each CU can overlap with ZERO change in traffic, LDS, or rounding.
//  - jb via readfirstlane -> SGPR -> W/bias loads stay scalar (r7 lesson).
template <int OUTF, int JBLK>
__global__ __launch_bounds__(512) void k_gemm_tile(
    const float* __restrict__ sums, const float* __restrict__ cnt,
    const float* __restrict__ W, const float* __restrict__ bias,
    float* __restrict__ out)
{
  __shared__ float lds[64 * PADF];   // 17408 B, one t-slice of 64 nodes
  const int tid = threadIdx.x;
  const int lane = tid & 63;
  const int n0 = blockIdx.x * 64;
  const int jb = __builtin_amdgcn_readfirstlane(tid >> 6) * JBLK;

  int n = n0 + lane;
  const bool valid = (n < N_NODES);
  if (!valid) n = N_NODES - 1;

  float acc[JBLK];
  #pragma unroll
  for (int j = 0; j < JBLK; ++j) acc[j] = bias[jb + j];

  #pragma unroll 1
  for (int t = 0; t < T_STEPS; ++t) {
    __syncthreads();   // previous tile fully consumed before overwrite
    // stage t-slice: 64 rows x 16 quads = 1024 items, 2 per thread, coalesced
    #pragma unroll
    for (int it = 0; it < 2; ++it) {
      const int item = tid + it * 512;
      const int q = item & 15;
      const int u = item >> 4;
      const int nn = n0 + u;
      float4 v = make_float4(0.f, 0.f, 0.f, 0.f);
      if (nn < N_NODES)
        v = *(const float4*)(sums + ((size_t)t * N_NODES + nn) * FDIM + q * 4);
      *(float4*)(lds + u * PADF + q * 4) = v;
    }
    __syncthreads();

    // ---- pass A for this t (verbatim r1 rounding) ----
    const float c  = cnt[(size_t)t * N_NODES + n];
    const float rc = 1.0f / fmaxf(c, 1.0f);
    const float4* row = (const float4*)(lds + lane * PADF);
    float ss = 0.0f;
    #pragma unroll
    for (int q = 0; q < FDIM / 4; ++q) {
      float4 v = row[q];
      float m0 = v.x * rc, m1 = v.y * rc, m2 = v.z * rc, m3 = v.w * rc;
      ss += m0 * m0 + m1 * m1 + m2 * m2 + m3 * m3;
    }
    const float norm = 1.0f - C2 * ss;
    const float s = rc / norm;

    // ---- pass B partial for this t, j-slice [jb, jb+JBLK) ----
    #pragma unroll
    for (int q8 = 0; q8 < FDIM / 8; ++q8) {
      const float4 a = row[q8 * 2 + 0];
      const float4 b4 = row[q8 * 2 + 1];
      const float hv[8] = {a.x, a.y, a.z, a.w, b4.x, b4.y, b4.z, b4.w};
      const float* wr = W + ((size_t)t * FDIM + q8 * 8) * OUTF + jb;
      #pragma unroll
      for (int i = 0; i < 8; ++i) {
        const float hs = hv[i] * s;
        #pragma unroll
        for (int j = 0; j < JBLK; ++j)
          acc[j] = fmaf(hs, wr[i * OUTF + j], acc[j]);
      }
    }
  }

  if (valid) {
    float* o = out + (size_t)n * OUTF + jb;
    #pragma unroll
    for (int j = 0; j < JBLK; ++j) o[j] = fmaxf(acc[j], 0.0f);
  }
}

extern "C" void kernel_launch(void* const* d_in, const int* in_sizes, int n_in,
                              void* d_out, int out_size, void* d_ws, size_t ws_size,
                              hipStream_t stream) {
  const float* x  = (const float*)d_in[0];
  const int*  ei  = (const int*)d_in[1];
  const int*  tix = (const int*)d_in[2];
  const float* W1 = (const float*)d_in[3];
  const float* b1 = (const float*)d_in[4];
  const float* W2 = (const float*)d_in[5];
  const float* b2 = (const float*)d_in[6];

  const int* src = ei;
  const int* dst = ei + N_EDGES;

  // Workspace: head[SEG] | nxt[NE] | sums[SEG*64] | cnt[SEG] | h1[NN*64]
  int*   head = (int*)d_ws;
  int*   nxt  = head + SEG;
  float* sums = (float*)(nxt + N_EDGES);
  float* cnt  = sums + (size_t)SEG * FDIM;
  float* h1   = cnt + SEG;

  const int sum_grid = (N_NODES + 3) / 4;        // k_sum6: 4 waves/block
  const int ngrp     = (N_NODES + 63) / 64;      // 1563 64-node groups

  hipMemsetAsync(head, 0xFF, (size_t)SEG * sizeof(int), stream);
  k_build<<<(N_EDGES + 255) / 256, 256, 0, stream>>>(dst, tix, head, nxt);

  // Layer 1
  k_sum6<<<sum_grid, 256, 0, stream>>>(x, src, head, nxt, sums, cnt);
  k_gemm_tile<64, 8><<<ngrp, 512, 0, stream>>>(sums, cnt, W1, b1, h1);

  // Layer 2 (same edge lists; cnt identical but rewritten -- harmless)
  k_sum6<<<sum_grid, 256, 0, stream>>>(h1, src, head, nxt, sums, cnt);
  k_gemm_tile<16, 2><<<ngrp, 512, 0, stream>>>(sums, cnt, W2, b2, (float*)d_out);
}

// Round 16
// 491.572 us; speedup vs baseline: 1.6370x; 1.2857x over previous
//
#include <hip/hip_runtime.h>

#define N_NODES 100000
#define N_EDGES 1600000
#define T_STEPS 6
#define FDIM    64
#define SEG     (T_STEPS * N_NODES)
#define C2      0.01f
#define PADF    68   // LDS row stride: 17 quads, 16B-aligned float4 rows

// Build per-(t,dst)-segment linked lists over edges. One atomicExch per edge
// on the 2.4MB head array (L2-resident).
__global__ __launch_bounds__(256) void k_build(
    const int* __restrict__ dst, const int* __restrict__ tix,
    int* __restrict__ head, int* __restrict__ nxt)
{
  const int e = blockIdx.x * blockDim.x + threadIdx.x;
  if (e >= N_EDGES) return;
  const int key = tix[e] * N_NODES + dst[e];
  nxt[e] = atomicExch(&head[key], e);
}

// ===== VERBATIM r13 k_sum6 (branchless 6-chain interleave, ~116us) =====
__global__ __launch_bounds__(256) void k_sum6(
    const float* __restrict__ feat, const int* __restrict__ src,
    const int* __restrict__ head, const int* __restrict__ nxt,
    float* __restrict__ sums, float* __restrict__ cnt)
{
  const int lane = threadIdx.x & 63;
  const int n = blockIdx.x * (blockDim.x >> 6) + (threadIdx.x >> 6);
  if (n >= N_NODES) return;

  int e0 = head[(size_t)0 * N_NODES + n];
  int e1 = head[(size_t)1 * N_NODES + n];
  int e2 = head[(size_t)2 * N_NODES + n];
  int e3 = head[(size_t)3 * N_NODES + n];
  int e4 = head[(size_t)4 * N_NODES + n];
  int e5 = head[(size_t)5 * N_NODES + n];

  float v0 = 0.f, v1 = 0.f, v2 = 0.f, v3 = 0.f, v4 = 0.f, v5 = 0.f;
  int c0 = 0, c1 = 0, c2 = 0, c3 = 0, c4 = 0, c5 = 0;

  while ((e0 >= 0) | (e1 >= 0) | (e2 >= 0) | (e3 >= 0) | (e4 >= 0) | (e5 >= 0)) {
    const int a0 = e0 < 0 ? 0 : e0, a1 = e1 < 0 ? 0 : e1, a2 = e2 < 0 ? 0 : e2;
    const int a3 = e3 < 0 ? 0 : e3, a4 = e4 < 0 ? 0 : e4, a5 = e5 < 0 ? 0 : e5;

    const int s0 = src[a0], s1 = src[a1], s2 = src[a2];
    const int s3 = src[a3], s4 = src[a4], s5 = src[a5];
    const int x0 = nxt[a0], x1 = nxt[a1], x2 = nxt[a2];
    const int x3 = nxt[a3], x4 = nxt[a4], x5 = nxt[a5];

    const float f0 = feat[(size_t)s0 * FDIM + lane];
    const float f1 = feat[(size_t)s1 * FDIM + lane];
    const float f2 = feat[(size_t)s2 * FDIM + lane];
    const float f3 = feat[(size_t)s3 * FDIM + lane];
    const float f4 = feat[(size_t)s4 * FDIM + lane];
    const float f5 = feat[(size_t)s5 * FDIM + lane];

    v0 += (e0 >= 0) ? f0 : 0.0f;  c0 += (e0 >= 0);  e0 = (e0 >= 0) ? x0 : -1;
    v1 += (e1 >= 0) ? f1 : 0.0f;  c1 += (e1 >= 0);  e1 = (e1 >= 0) ? x1 : -1;
    v2 += (e2 >= 0) ? f2 : 0.0f;  c2 += (e2 >= 0);  e2 = (e2 >= 0) ? x2 : -1;
    v3 += (e3 >= 0) ? f3 : 0.0f;  c3 += (e3 >= 0);  e3 = (e3 >= 0) ? x3 : -1;
    v4 += (e4 >= 0) ? f4 : 0.0f;  c4 += (e4 >= 0);  e4 = (e4 >= 0) ? x4 : -1;
    v5 += (e5 >= 0) ? f5 : 0.0f;  c5 += (e5 >= 0);  e5 = (e5 >= 0) ? x5 : -1;
  }

  sums[((size_t)0 * N_NODES + n) * FDIM + lane] = v0;
  sums[((size_t)1 * N_NODES + n) * FDIM + lane] = v1;
  sums[((size_t)2 * N_NODES + n) * FDIM + lane] = v2;
  sums[((size_t)3 * N_NODES + n) * FDIM + lane] = v3;
  sums[((size_t)4 * N_NODES + n) * FDIM + lane] = v4;
  sums[((size_t)5 * N_NODES + n) * FDIM + lane] = v5;
  if (lane == 0) {
    cnt[(size_t)0 * N_NODES + n] = (float)c0;
    cnt[(size_t)1 * N_NODES + n] = (float)c1;
    cnt[(size_t)2 * N_NODES + n] = (float)c2;
    cnt[(size_t)3 * N_NODES + n] = (float)c3;
    cnt[(size_t)4 * N_NODES + n] = (float)c4;
    cnt[(size_t)5 * N_NODES + n] = (float)c5;
  }
}

// r13 gemm (4 waves x JBLK=OUTF/4, 256 threads -- the proven 147us config;
// r15 falsified 8-wave blocks, r14 falsified runtime-indexed dbuf), with ONE
// change: stage TWO t-planes per barrier round. All 8 float4 loads issue in
// one clause (2x MLP per wait) and barrier count halves 12 -> 6 -- directly
// attacks the measured stage-latency bound (gemm<16>==gemm<64>==147us,
// VALUBusy 33%). LDS is static [2][...] with compile-time plane indices.
// Planes computed t-ascending; pass A/B chains verbatim -> absmax unchanged.
template <int OUTF, int JBLK>
__global__ __launch_bounds__(256) void k_gemm_tile2(
    const float* __restrict__ sums, const float* __restrict__ cnt,
    const float* __restrict__ W, const float* __restrict__ bias,
    float* __restrict__ out)
{
  __shared__ float lds[2][64 * PADF];   // 2 planes x 17408 B
  const int tid = threadIdx.x;
  const int lane = tid & 63;
  const int n0 = blockIdx.x * 64;
  const int jb = __builtin_amdgcn_readfirstlane(tid >> 6) * JBLK;

  int n = n0 + lane;
  const bool valid = (n < N_NODES);
  if (!valid) n = N_NODES - 1;

  float acc[JBLK];
  #pragma unroll
  for (int j = 0; j < JBLK; ++j) acc[j] = bias[jb + j];

  #pragma unroll 1
  for (int tp = 0; tp < T_STEPS / 2; ++tp) {
    __syncthreads();   // previous pair fully consumed before overwrite
    // stage planes t=2tp, 2tp+1: 2048 items, 8 per thread, all loads first
    float4 reg[8];
    #pragma unroll
    for (int it = 0; it < 8; ++it) {
      const int item = tid + it * 256;
      const int q = item & 15;
      const int u = (item >> 4) & 63;
      const int pl = item >> 10;
      const int nn = n0 + u;
      reg[it] = make_float4(0.f, 0.f, 0.f, 0.f);
      if (nn < N_NODES)
        reg[it] = *(const float4*)(sums + ((size_t)(2 * tp + pl) * N_NODES + nn) * FDIM + q * 4);
    }
    #pragma unroll
    for (int it = 0; it < 8; ++it) {
      const int item = tid + it * 256;
      const int q = item & 15;
      const int u = (item >> 4) & 63;
      const int pl = item >> 10;
      *(float4*)(&lds[pl][u * PADF + q * 4]) = reg[it];
    }
    __syncthreads();

    #pragma unroll
    for (int pl = 0; pl < 2; ++pl) {
      const int t = 2 * tp + pl;

      // ---- pass A for this t (verbatim r1 rounding) ----
      const float c  = cnt[(size_t)t * N_NODES + n];
      const float rc = 1.0f / fmaxf(c, 1.0f);
      const float4* row = (const float4*)(&lds[pl][lane * PADF]);
      float ss = 0.0f;
      #pragma unroll
      for (int q = 0; q < FDIM / 4; ++q) {
        float4 v = row[q];
        float m0 = v.x * rc, m1 = v.y * rc, m2 = v.z * rc, m3 = v.w * rc;
        ss += m0 * m0 + m1 * m1 + m2 * m2 + m3 * m3;
      }
      const float norm = 1.0f - C2 * ss;
      const float s = rc / norm;

      // ---- pass B partial for this t, j-slice [jb, jb+JBLK) ----
      #pragma unroll
      for (int q8 = 0; q8 < FDIM / 8; ++q8) {
        const float4 a = row[q8 * 2 + 0];
        const float4 b4 = row[q8 * 2 + 1];
        const float hv[8] = {a.x, a.y, a.z, a.w, b4.x, b4.y, b4.z, b4.w};
        const float* wr = W + ((size_t)t * FDIM + q8 * 8) * OUTF + jb;
        #pragma unroll
        for (int i = 0; i < 8; ++i) {
          const float hs = hv[i] * s;
          #pragma unroll
          for (int j = 0; j < JBLK; ++j)
            acc[j] = fmaf(hs, wr[i * OUTF + j], acc[j]);
        }
      }
    }
  }

  if (valid) {
    float* o = out + (size_t)n * OUTF + jb;
    #pragma unroll
    for (int j = 0; j < JBLK; ++j) o[j] = fmaxf(acc[j], 0.0f);
  }
}

extern "C" void kernel_launch(void* const* d_in, const int* in_sizes, int n_in,
                              void* d_out, int out_size, void* d_ws, size_t ws_size,
                              hipStream_t stream) {
  const float* x  = (const float*)d_in[0];
  const int*  ei  = (const int*)d_in[1];
  const int*  tix = (const int*)d_in[2];
  const float* W1 = (const float*)d_in[3];
  const float* b1 = (const float*)d_in[4];
  const float* W2 = (const float*)d_in[5];
  const float* b2 = (const float*)d_in[6];

  const int* src = ei;
  const int* dst = ei + N_EDGES;

  // Workspace: head[SEG] | nxt[NE] | sums[SEG*64] | cnt[SEG] | h1[NN*64]
  int*   head = (int*)d_ws;
  int*   nxt  = head + SEG;
  float* sums = (float*)(nxt + N_EDGES);
  float* cnt  = sums + (size_t)SEG * FDIM;
  float* h1   = cnt + SEG;

  const int sum_grid = (N_NODES + 3) / 4;        // k_sum6: 4 waves/block
  const int ngrp     = (N_NODES + 63) / 64;      // 1563 64-node groups

  hipMemsetAsync(head, 0xFF, (size_t)SEG * sizeof(int), stream);
  k_build<<<(N_EDGES + 255) / 256, 256, 0, stream>>>(dst, tix, head, nxt);

  // Layer 1
  k_sum6<<<sum_grid, 256, 0, stream>>>(x, src, head, nxt, sums, cnt);
  k_gemm_tile2<64, 16><<<ngrp, 256, 0, stream>>>(sums, cnt, W1, b1, h1);

  // Layer 2 (same edge lists; cnt identical but rewritten -- harmless)
  k_sum6<<<sum_grid, 256, 0, stream>>>(h1, src, head, nxt, sums, cnt);
  k_gemm_tile2<16, 4><<<ngrp, 256, 0, stream>>>(sums, cnt, W2, b2, (float*)d_out);
}

// Round 17
// 467.962 us; speedup vs baseline: 1.7196x; 1.0505x over previous
//
#include <hip/hip_runtime.h>

#define N_NODES 100000
#define N_EDGES 1600000
#define T_STEPS 6
#define FDIM    64
#define SEG     (T_STEPS * N_NODES)
#define C2      0.01f
#define PADF    68   // LDS row stride: 17 quads, 16B-aligned float4 rows

// Build per-(t,dst)-segment linked lists over edges. One atomicExch per edge
// on the 2.4MB head array (L2-resident).
__global__ __launch_bounds__(256) void k_build(
    const int* __restrict__ dst, const int* __restrict__ tix,
    int* __restrict__ head, int* __restrict__ nxt)
{
  const int e = blockIdx.x * blockDim.x + threadIdx.x;
  if (e >= N_EDGES) return;
  const int key = tix[e] * N_NODES + dst[e];
  nxt[e] = atomicExch(&head[key], e);
}

// r13/r16 k_sum6 with SCALARIZED chains. The 6 chain pointers are wave-
// uniform (seg = wave id), but r16's VALUBusy=70% showed the compiler
// replicating all chain/address math across 64 lanes (e comes from loads,
// so divergence analysis assumes divergent). readfirstlane (an identity
// here) pins e0..e5 to SGPRs: src/nxt loads become s_load, feat row
// addresses become SGPR-base + invariant lane*4 (saddr form), chain
// compares/selects move to the scalar pipe. Same values, same add order
// -> sums/cnt bit-identical to r5-r16.
__global__ __launch_bounds__(256) void k_sum6(
    const float* __restrict__ feat, const int* __restrict__ src,
    const int* __restrict__ head, const int* __restrict__ nxt,
    float* __restrict__ sums, float* __restrict__ cnt)
{
  const int lane = threadIdx.x & 63;
  const int n = blockIdx.x * (blockDim.x >> 6) + (threadIdx.x >> 6);
  if (n >= N_NODES) return;

  int e0 = __builtin_amdgcn_readfirstlane(head[(size_t)0 * N_NODES + n]);
  int e1 = __builtin_amdgcn_readfirstlane(head[(size_t)1 * N_NODES + n]);
  int e2 = __builtin_amdgcn_readfirstlane(head[(size_t)2 * N_NODES + n]);
  int e3 = __builtin_amdgcn_readfirstlane(head[(size_t)3 * N_NODES + n]);
  int e4 = __builtin_amdgcn_readfirstlane(head[(size_t)4 * N_NODES + n]);
  int e5 = __builtin_amdgcn_readfirstlane(head[(size_t)5 * N_NODES + n]);

  float v0 = 0.f, v1 = 0.f, v2 = 0.f, v3 = 0.f, v4 = 0.f, v5 = 0.f;
  int c0 = 0, c1 = 0, c2 = 0, c3 = 0, c4 = 0, c5 = 0;

  while ((e0 >= 0) | (e1 >= 0) | (e2 >= 0) | (e3 >= 0) | (e4 >= 0) | (e5 >= 0)) {
    const int a0 = e0 < 0 ? 0 : e0, a1 = e1 < 0 ? 0 : e1, a2 = e2 < 0 ? 0 : e2;
    const int a3 = e3 < 0 ? 0 : e3, a4 = e4 < 0 ? 0 : e4, a5 = e5 < 0 ? 0 : e5;

    const int s0 = __builtin_amdgcn_readfirstlane(src[a0]);
    const int s1 = __builtin_amdgcn_readfirstlane(src[a1]);
    const int s2 = __builtin_amdgcn_readfirstlane(src[a2]);
    const int s3 = __builtin_amdgcn_readfirstlane(src[a3]);
    const int s4 = __builtin_amdgcn_readfirstlane(src[a4]);
    const int s5 = __builtin_amdgcn_readfirstlane(src[a5]);
    const int x0 = __builtin_amdgcn_readfirstlane(nxt[a0]);
    const int x1 = __builtin_amdgcn_readfirstlane(nxt[a1]);
    const int x2 = __builtin_amdgcn_readfirstlane(nxt[a2]);
    const int x3 = __builtin_amdgcn_readfirstlane(nxt[a3]);
    const int x4 = __builtin_amdgcn_readfirstlane(nxt[a4]);
    const int x5 = __builtin_amdgcn_readfirstlane(nxt[a5]);

    const float f0 = feat[(size_t)s0 * FDIM + lane];
    const float f1 = feat[(size_t)s1 * FDIM + lane];
    const float f2 = feat[(size_t)s2 * FDIM + lane];
    const float f3 = feat[(size_t)s3 * FDIM + lane];
    const float f4 = feat[(size_t)s4 * FDIM + lane];
    const float f5 = feat[(size_t)s5 * FDIM + lane];

    v0 += (e0 >= 0) ? f0 : 0.0f;  c0 += (e0 >= 0);  e0 = (e0 >= 0) ? x0 : -1;
    v1 += (e1 >= 0) ? f1 : 0.0f;  c1 += (e1 >= 0);  e1 = (e1 >= 0) ? x1 : -1;
    v2 += (e2 >= 0) ? f2 : 0.0f;  c2 += (e2 >= 0);  e2 = (e2 >= 0) ? x2 : -1;
    v3 += (e3 >= 0) ? f3 : 0.0f;  c3 += (e3 >= 0);  e3 = (e3 >= 0) ? x3 : -1;
    v4 += (e4 >= 0) ? f4 : 0.0f;  c4 += (e4 >= 0);  e4 = (e4 >= 0) ? x4 : -1;
    v5 += (e5 >= 0) ? f5 : 0.0f;  c5 += (e5 >= 0);  e5 = (e5 >= 0) ? x5 : -1;
  }

  sums[((size_t)0 * N_NODES + n) * FDIM + lane] = v0;
  sums[((size_t)1 * N_NODES + n) * FDIM + lane] = v1;
  sums[((size_t)2 * N_NODES + n) * FDIM + lane] = v2;
  sums[((size_t)3 * N_NODES + n) * FDIM + lane] = v3;
  sums[((size_t)4 * N_NODES + n) * FDIM + lane] = v4;
  sums[((size_t)5 * N_NODES + n) * FDIM + lane] = v5;
  if (lane == 0) {
    cnt[(size_t)0 * N_NODES + n] = (float)c0;
    cnt[(size_t)1 * N_NODES + n] = (float)c1;
    cnt[(size_t)2 * N_NODES + n] = (float)c2;
    cnt[(size_t)3 * N_NODES + n] = (float)c3;
    cnt[(size_t)4 * N_NODES + n] = (float)c4;
    cnt[(size_t)5 * N_NODES + n] = (float)c5;
  }
}

// ===== VERBATIM r16 gemm (two-plane staging; proven win 147 -> ~100us) =====
template <int OUTF, int JBLK>
__global__ __launch_bounds__(256) void k_gemm_tile2(
    const float* __restrict__ sums, const float* __restrict__ cnt,
    const float* __restrict__ W, const float* __restrict__ bias,
    float* __restrict__ out)
{
  __shared__ float lds[2][64 * PADF];   // 2 planes x 17408 B
  const int tid = threadIdx.x;
  const int lane = tid & 63;
  const int n0 = blockIdx.x * 64;
  const int jb = __builtin_amdgcn_readfirstlane(tid >> 6) * JBLK;

  int n = n0 + lane;
  const bool valid = (n < N_NODES);
  if (!valid) n = N_NODES - 1;

  float acc[JBLK];
  #pragma unroll
  for (int j = 0; j < JBLK; ++j) acc[j] = bias[jb + j];

  #pragma unroll 1
  for (int tp = 0; tp < T_STEPS / 2; ++tp) {
    __syncthreads();   // previous pair fully consumed before overwrite
    // stage planes t=2tp, 2tp+1: 2048 items, 8 per thread, all loads first
    float4 reg[8];
    #pragma unroll
    for (int it = 0; it < 8; ++it) {
      const int item = tid + it * 256;
      const int q = item & 15;
      const int u = (item >> 4) & 63;
      const int pl = item >> 10;
      const int nn = n0 + u;
      reg[it] = make_float4(0.f, 0.f, 0.f, 0.f);
      if (nn < N_NODES)
        reg[it] = *(const float4*)(sums + ((size_t)(2 * tp + pl) * N_NODES + nn) * FDIM + q * 4);
    }
    #pragma unroll
    for (int it = 0; it < 8; ++it) {
      const int item = tid + it * 256;
      const int q = item & 15;
      const int u = (item >> 4) & 63;
      const int pl = item >> 10;
      *(float4*)(&lds[pl][u * PADF + q * 4]) = reg[it];
    }
    __syncthreads();

    #pragma unroll
    for (int pl = 0; pl < 2; ++pl) {
      const int t = 2 * tp + pl;

      // ---- pass A for this t (verbatim r1 rounding) ----
      const float c  = cnt[(size_t)t * N_NODES + n];
      const float rc = 1.0f / fmaxf(c, 1.0f);
      const float4* row = (const float4*)(&lds[pl][lane * PADF]);
      float ss = 0.0f;
      #pragma unroll
      for (int q = 0; q < FDIM / 4; ++q) {
        float4 v = row[q];
        float m0 = v.x * rc, m1 = v.y * rc, m2 = v.z * rc, m3 = v.w * rc;
        ss += m0 * m0 + m1 * m1 + m2 * m2 + m3 * m3;
      }
      const float norm = 1.0f - C2 * ss;
      const float s = rc / norm;

      // ---- pass B partial for this t, j-slice [jb, jb+JBLK) ----
      #pragma unroll
      for (int q8 = 0; q8 < FDIM / 8; ++q8) {
        const float4 a = row[q8 * 2 + 0];
        const float4 b4 = row[q8 * 2 + 1];
        const float hv[8] = {a.x, a.y, a.z, a.w, b4.x, b4.y, b4.z, b4.w};
        const float* wr = W + ((size_t)t * FDIM + q8 * 8) * OUTF + jb;
        #pragma unroll
        for (int i = 0; i < 8; ++i) {
          const float hs = hv[i] * s;
          #pragma unroll
          for (int j = 0; j < JBLK; ++j)
            acc[j] = fmaf(hs, wr[i * OUTF + j], acc[j]);
        }
      }
    }
  }

  if (valid) {
    float* o = out + (size_t)n * OUTF + jb;
    #pragma unroll
    for (int j = 0; j < JBLK; ++j) o[j] = fmaxf(acc[j], 0.0f);
  }
}

extern "C" void kernel_launch(void* const* d_in, const int* in_sizes, int n_in,
                              void* d_out, int out_size, void* d_ws, size_t ws_size,
                              hipStream_t stream) {
  const float* x  = (const float*)d_in[0];
  const int*  ei  = (const int*)d_in[1];
  const int*  tix = (const int*)d_in[2];
  const float* W1 = (const float*)d_in[3];
  const float* b1 = (const float*)d_in[4];
  const float* W2 = (const float*)d_in[5];
  const float* b2 = (const float*)d_in[6];

  const int* src = ei;
  const int* dst = ei + N_EDGES;

  // Workspace: head[SEG] | nxt[NE] | sums[SEG*64] | cnt[SEG] | h1[NN*64]
  int*   head = (int*)d_ws;
  int*   nxt  = head + SEG;
  float* sums = (float*)(nxt + N_EDGES);
  float* cnt  = sums + (size_t)SEG * FDIM;
  float* h1   = cnt + SEG;

  const int sum_grid = (N_NODES + 3) / 4;        // k_sum6: 4 waves/block
  const int ngrp     = (N_NODES + 63) / 64;      // 1563 64-node groups

  hipMemsetAsync(head, 0xFF, (size_t)SEG * sizeof(int), stream);
  k_build<<<(N_EDGES + 255) / 256, 256, 0, stream>>>(dst, tix, head, nxt);

  // Layer 1
  k_sum6<<<sum_grid, 256, 0, stream>>>(x, src, head, nxt, sums, cnt);
  k_gemm_tile2<64, 16><<<ngrp, 256, 0, stream>>>(sums, cnt, W1, b1, h1);

  // Layer 2 (same edge lists; cnt identical but rewritten -- harmless)
  k_sum6<<<sum_grid, 256, 0, stream>>>(h1, src, head, nxt, sums, cnt);
  k_gemm_tile2<16, 4><<<ngrp, 256, 0, stream>>>(sums, cnt, W2, b2, (float*)d_out);
}